// Round 1
// 919.735 us; speedup vs baseline: 1.0008x; 1.0008x over previous
//
#include <hip/hip_runtime.h>
#include <hip/hip_bf16.h>

// Problem constants (from reference)
#define NND   20000
#define TSTEP 64
#define FF    128
#define BB    8192
#define KK    32
#define QQ    (3*BB)      // 24576
#define WWINC 64
#define DDIM  16
#define MDIM  64          // msg dim
#define HDIM  128         // hidden dim
#define HHDIM 64          // h dim

typedef __attribute__((ext_vector_type(8)))  short short8;   // 8 bf16 (4 VGPRs)
typedef __attribute__((ext_vector_type(16))) float f32x16;   // 32x32 MFMA acc

union FragU { unsigned u[4]; short8 s; };

// fp32 -> bf16 (RNE), packed pair -> one dword
static __device__ __forceinline__ unsigned pkbf(float a, float b) {
    union { float f; unsigned u; } ua, ub; ua.f = a; ub.f = b;
    unsigned ra = (ua.u + 0x7FFFu + ((ua.u >> 16) & 1u)) >> 16;
    unsigned rb = (ub.u + 0x7FFFu + ((ub.u >> 16) & 1u)) >> 16;
    return (ra & 0xFFFFu) | (rb << 16);
}
static __device__ __forceinline__ short f2bf(float a) {
    union { float f; unsigned u; } v; v.f = a;
    return (short)((v.u + 0x7FFFu + ((v.u >> 16) & 1u)) >> 16);
}

// ---------------------------------------------------------------------------
// Weight pre-pack: cw1[256x128], cw2[128x64], sw1[rows 0..191][128] -> bf16
// B-fragment order. frag f, lane ln holds B[k=16s+8*(ln>>5)+i][col=32n+(ln&31)].
// 8192 threads, one 16B frag-slice each.
// ---------------------------------------------------------------------------
__global__ void pack_kernel(const float* __restrict__ cw1, const float* __restrict__ cw2,
                            const float* __restrict__ sw1,
                            short* __restrict__ cw1f, short* __restrict__ cw2f,
                            short* __restrict__ sw1f)
{
    const int gid = blockIdx.x * 256 + threadIdx.x;   // 0..8191
    const int ln  = gid & 63;
    const int f   = gid >> 6;                         // 0..127
    const int kr8 = 8 * (ln >> 5);
    const int c   = ln & 31;
    FragU v;
    if (f < 64) {            // cw1: 16 K-steps x 4 N-tiles
        const int s = f >> 2, n = f & 3;
        #pragma unroll
        for (int i = 0; i < 8; i += 2)
            v.u[i >> 1] = pkbf(cw1[(16*s + kr8 + i)     * HDIM + 32*n + c],
                               cw1[(16*s + kr8 + i + 1) * HDIM + 32*n + c]);
        *(short8*)&cw1f[f * 512 + ln * 8] = v.s;
    } else if (f < 80) {     // cw2: 8 K-steps x 2 N-tiles
        const int f2 = f - 64, s = f2 >> 1, n = f2 & 1;
        #pragma unroll
        for (int i = 0; i < 8; i += 2)
            v.u[i >> 1] = pkbf(cw2[(16*s + kr8 + i)     * HHDIM + 32*n + c],
                               cw2[(16*s + kr8 + i + 1) * HHDIM + 32*n + c]);
        *(short8*)&cw2f[f2 * 512 + ln * 8] = v.s;
    } else {                 // sw1 (rows 0..191): 12 K-steps x 4 N-tiles
        const int f3 = f - 80, s = f3 >> 2, n = f3 & 3;
        #pragma unroll
        for (int i = 0; i < 8; i += 2)
            v.u[i >> 1] = pkbf(sw1[(16*s + kr8 + i)     * HDIM + 32*n + c],
                               sw1[(16*s + kr8 + i + 1) * HDIM + 32*n + c]);
        *(short8*)&sw1f[f3 * 512 + ln * 8] = v.s;
    }
}

// ---------------------------------------------------------------------------
// Fused MFMA edge aggregation (both signs in one launch).
// Restructured: mean(relu(H)@W2) == mean(relu(H)) @ W2, so W2 is applied ONCE
// per block over the 32 accumulated per-q mean rows instead of per-edge-tile.
// Per-q epilogue is now 32 fma-relu + 2 shfl + 1 LDS b16 write.
// Index prefetch (1-ahead) takes the idx gather off the per-q critical path.
// ---------------------------------------------------------------------------
#define NW     4
#define AGRID  768                 // blocks per sign
#define NWAVES (AGRID * NW)        // 3072 waves per sign -> 8 q per wave
#define MLD    72                  // mean-row stride in bf16 (breaks 32-way bank conflict)

__global__ __launch_bounds__(256, 4)
void agg_fused_kernel(const float* __restrict__ x, const float* __restrict__ demb,
                      const float* __restrict__ piw1, const float* __restrict__ pib1,
                      const float* __restrict__ piw2, const float* __restrict__ pib2,
                      const float* __restrict__ pow1, const float* __restrict__ pob1,
                      const float* __restrict__ pow2, const float* __restrict__ pob2,
                      const int* __restrict__ times,
                      const int* __restrict__ iu, const int* __restrict__ it, const int* __restrict__ im,
                      const int* __restrict__ ou, const int* __restrict__ ot, const int* __restrict__ om,
                      float* __restrict__ min_ws, float* __restrict__ mout_ws)
{
    __shared__ short w1f[9 * 2 * 64 * 8];   // 18.4 KB
    __shared__ short meanb[32 * MLD];       // 4.6 KB: 32 q-rows x 64 cols (bf16, padded)
    __shared__ int   qidxL[32];
    __shared__ float hasL[32];

    const int half = (blockIdx.x >= AGRID) ? 1 : 0;
    const int bid  = blockIdx.x - half * AGRID;
    const float* w1 = half ? pow1 : piw1;
    const float* b1 = half ? pob1 : pib1;
    const float* w2 = half ? pow2 : piw2;
    const float* b2 = half ? pob2 : pib2;
    const int* uu = half ? ou : iu;
    const int* tt = half ? ot : it;
    const int* mm = half ? om : im;
    float* mo = half ? mout_ws : min_ws;
    const int sg = half ? -1 : 1;

    const int tid  = threadIdx.x;
    const int lane = tid & 63;
    const int wv   = tid >> 6;
    const int r    = lane & 31;
    const int hi   = lane >> 5;

    // stage W1 (144x64) as bf16 B-fragments in LDS
    for (int f = tid; f < 9 * 2 * 64; f += 256) {
        const int ln = f & 63, sn = f >> 6, s = sn >> 1, n = sn & 1;
        const int krow = 16 * s + 8 * (ln >> 5);
        const int col  = 32 * n + (ln & 31);
        #pragma unroll
        for (int i = 0; i < 8; i += 2) {
            const float va = w1[(krow + i) * MDIM + col];
            const float vb = w1[(krow + i + 1) * MDIM + col];
            *(unsigned*)&w1f[f * 8 + i] = pkbf(va, vb);
        }
    }
    const float b1c0 = b1[r], b1c1 = b1[32 + r];
    __syncthreads();

    const int gwave = bid * NW + wv;
    int q = gwave;

    // prefetch iteration-0 indices
    int pu = 0, ptau = 0, pmk = 0;
    if (lane < KK) {
        pu   = uu[q * KK + lane];
        ptau = tt[q * KK + lane];
        pmk  = mm[q * KK + lane];
    }
    int ptq = times[q];

    for (int qi = 0; qi < 8; qi++) {
        const int t   = ptq;
        const int mk  = pmk;
        int d = sg * (t - ptau);
        d = d < 0 ? 0 : (d > WWINC ? WWINC : d);
        const int xb = pu * (TSTEP * FF) + ptau * FF;
        const int db = d * DDIM;
        const int qcur = q;

        // issue next q's index gathers before this q's compute (pipeline)
        if (qi < 7) {
            q += NWAVES;
            if (lane < KK) {
                pu   = uu[q * KK + lane];
                ptau = tt[q * KK + lane];
                pmk  = mm[q * KK + lane];
            }
            ptq = times[q];
        }

        const unsigned long long bal = __ballot(mk != 0);
        const float cnt  = (float)__popcll(bal);
        const float cinv = 1.0f / fmaxf(cnt, 1.0f);
        const float has  = cnt > 0.0f ? 1.0f : 0.0f;
        const int xbr = __shfl(xb, r, 64);
        const int dbr = __shfl(db, r, 64);
        const int mkr = __shfl(mk, r, 64);

        f32x16 acc0, acc1;
        #pragma unroll
        for (int i = 0; i < 16; i++) { acc0[i] = 0.0f; acc1[i] = 0.0f; }

        const float* xrow = x + xbr + 8 * hi;
        #pragma unroll 4
        for (int s = 0; s < 8; s++) {
            float4 p0 = make_float4(0.f, 0.f, 0.f, 0.f), p1 = p0;
            if (mkr) {
                p0 = *(const float4*)(xrow + 16 * s);
                p1 = *(const float4*)(xrow + 16 * s + 4);
            }
            FragU fa;
            fa.u[0] = pkbf(p0.x, p0.y); fa.u[1] = pkbf(p0.z, p0.w);
            fa.u[2] = pkbf(p1.x, p1.y); fa.u[3] = pkbf(p1.z, p1.w);
            const short8 bf0 = *(const short8*)&w1f[(s * 2 + 0) * 512 + lane * 8];
            const short8 bf1 = *(const short8*)&w1f[(s * 2 + 1) * 512 + lane * 8];
            acc0 = __builtin_amdgcn_mfma_f32_32x32x16_bf16(fa.s, bf0, acc0, 0, 0, 0);
            acc1 = __builtin_amdgcn_mfma_f32_32x32x16_bf16(fa.s, bf1, acc1, 0, 0, 0);
        }
        {
            float4 p0 = make_float4(0.f, 0.f, 0.f, 0.f), p1 = p0;
            if (mkr) {
                p0 = *(const float4*)(demb + dbr + 8 * hi);
                p1 = *(const float4*)(demb + dbr + 8 * hi + 4);
            }
            FragU fa;
            fa.u[0] = pkbf(p0.x, p0.y); fa.u[1] = pkbf(p0.z, p0.w);
            fa.u[2] = pkbf(p1.x, p1.y); fa.u[3] = pkbf(p1.z, p1.w);
            const short8 bf0 = *(const short8*)&w1f[(8 * 2 + 0) * 512 + lane * 8];
            const short8 bf1 = *(const short8*)&w1f[(8 * 2 + 1) * 512 + lane * 8];
            acc0 = __builtin_amdgcn_mfma_f32_32x32x16_bf16(fa.s, bf0, acc0, 0, 0, 0);
            acc1 = __builtin_amdgcn_mfma_f32_32x32x16_bf16(fa.s, bf1, acc1, 0, 0, 0);
        }

        // epilogue: masked column-sum of relu(H + b1) -> mean row (bf16) in LDS
        float s0 = 0.0f, s1 = 0.0f;
        #pragma unroll
        for (int g = 0; g < 16; g++) {
            const int rr = (g & 3) + 8 * (g >> 2) + 4 * hi;
            const float mrow = (float)((bal >> rr) & 1ull);
            s0 = fmaf(fmaxf(acc0[g] + b1c0, 0.0f), mrow, s0);
            s1 = fmaf(fmaxf(acc1[g] + b1c1, 0.0f), mrow, s1);
        }
        s0 += __shfl_xor(s0, 32, 64);
        s1 += __shfl_xor(s1, 32, 64);
        const int row = wv * 8 + qi;
        meanb[row * MLD + lane] = f2bf((hi ? s1 : s0) * cinv);   // col = lane
        if (lane == 0) { qidxL[row] = qcur; hasL[row] = has; }
    }

    __syncthreads();

    // Block-level GEMM2: mean[32 x 64] @ W2[64 x 64]; waves 0/1 take col tiles 0/1.
    if (wv < 2) {
        f32x16 c;
        #pragma unroll
        for (int i = 0; i < 16; i++) c[i] = 0.0f;
        #pragma unroll
        for (int s = 0; s < 4; s++) {
            FragU fb;
            #pragma unroll
            for (int i = 0; i < 8; i += 2) {
                const float va = w2[(16 * s + 8 * hi + i)     * MDIM + 32 * wv + r];
                const float vb = w2[(16 * s + 8 * hi + i + 1) * MDIM + 32 * wv + r];
                fb.u[i >> 1] = pkbf(va, vb);
            }
            const short8 a = *(const short8*)&meanb[r * MLD + 16 * s + 8 * hi];
            c = __builtin_amdgcn_mfma_f32_32x32x16_bf16(a, fb.s, c, 0, 0, 0);
        }
        const float b2c = b2[32 * wv + r];
        #pragma unroll
        for (int g = 0; g < 16; g++) {
            const int rr = (g & 3) + 8 * (g >> 2) + 4 * hi;
            mo[(size_t)qidxL[rr] * MDIM + 32 * wv + r] = c[g] + b2c * hasL[rr];
        }
    }
}

// ---------------------------------------------------------------------------
// MFMA combine: [Q,256] @ cw1 -> relu -> @ cw2 -> relu -> h_bf (bf16 [Q,64]).
// One 32-q tile per 64-thread block; B-frags read pre-packed from global
// (16B/lane coalesced, L2-hot); H transposed through per-block LDS.
// ---------------------------------------------------------------------------
#define HLD2 136   // H row stride in bf16 (272B, 16B-aligned, 4-way b128 reads)

__global__ __launch_bounds__(64, 2)
void combine_mfma(const float* __restrict__ x,
                  const int* __restrict__ node_ids, const int* __restrict__ times,
                  const float* __restrict__ min_ws, const float* __restrict__ mout_ws,
                  const short* __restrict__ cw1f, const float* __restrict__ cb1,
                  const short* __restrict__ cw2f, const float* __restrict__ cb2,
                  short* __restrict__ h_bf)
{
    __shared__ short Hs[KK * HLD2];
    const int lane = threadIdx.x & 63;
    const int r = lane & 31, hi = lane >> 5;
    const int qb = blockIdx.x * 32;
    const int q  = qb + r;
    const int xb = node_ids[q] * (TSTEP * FF) + times[q] * FF;

    f32x16 acc[4];
    #pragma unroll
    for (int n = 0; n < 4; n++)
        #pragma unroll
        for (int i = 0; i < 16; i++) acc[n][i] = 0.0f;

    // K 0..127: x_vt
    const float* xrow = x + xb + 8 * hi;
    #pragma unroll
    for (int s = 0; s < 8; s++) {
        const float4 p0 = *(const float4*)(xrow + 16 * s);
        const float4 p1 = *(const float4*)(xrow + 16 * s + 4);
        FragU fa;
        fa.u[0] = pkbf(p0.x, p0.y); fa.u[1] = pkbf(p0.z, p0.w);
        fa.u[2] = pkbf(p1.x, p1.y); fa.u[3] = pkbf(p1.z, p1.w);
        #pragma unroll
        for (int n = 0; n < 4; n++) {
            const short8 bf = *(const short8*)&cw1f[(s * 4 + n) * 512 + lane * 8];
            acc[n] = __builtin_amdgcn_mfma_f32_32x32x16_bf16(fa.s, bf, acc[n], 0, 0, 0);
        }
    }
    // K 128..191: m_in
    const float* mrow = min_ws + (size_t)q * MDIM + 8 * hi;
    #pragma unroll
    for (int s = 0; s < 4; s++) {
        const float4 p0 = *(const float4*)(mrow + 16 * s);
        const float4 p1 = *(const float4*)(mrow + 16 * s + 4);
        FragU fa;
        fa.u[0] = pkbf(p0.x, p0.y); fa.u[1] = pkbf(p0.z, p0.w);
        fa.u[2] = pkbf(p1.x, p1.y); fa.u[3] = pkbf(p1.z, p1.w);
        #pragma unroll
        for (int n = 0; n < 4; n++) {
            const short8 bf = *(const short8*)&cw1f[((s + 8) * 4 + n) * 512 + lane * 8];
            acc[n] = __builtin_amdgcn_mfma_f32_32x32x16_bf16(fa.s, bf, acc[n], 0, 0, 0);
        }
    }
    // K 192..255: m_out
    const float* orow = mout_ws + (size_t)q * MDIM + 8 * hi;
    #pragma unroll
    for (int s = 0; s < 4; s++) {
        const float4 p0 = *(const float4*)(orow + 16 * s);
        const float4 p1 = *(const float4*)(orow + 16 * s + 4);
        FragU fa;
        fa.u[0] = pkbf(p0.x, p0.y); fa.u[1] = pkbf(p0.z, p0.w);
        fa.u[2] = pkbf(p1.x, p1.y); fa.u[3] = pkbf(p1.z, p1.w);
        #pragma unroll
        for (int n = 0; n < 4; n++) {
            const short8 bf = *(const short8*)&cw1f[((s + 12) * 4 + n) * 512 + lane * 8];
            acc[n] = __builtin_amdgcn_mfma_f32_32x32x16_bf16(fa.s, bf, acc[n], 0, 0, 0);
        }
    }

    // epilogue 1: relu + bias -> H (bf16, LDS)
    #pragma unroll
    for (int n = 0; n < 4; n++) {
        const float bias = cb1[32 * n + r];
        #pragma unroll
        for (int g = 0; g < 16; g++) {
            const int rr = (g & 3) + 8 * (g >> 2) + 4 * hi;
            Hs[rr * HLD2 + 32 * n + r] = f2bf(fmaxf(acc[n][g] + bias, 0.0f));
        }
    }
    __syncthreads();

    // GEMM2: H[32x128] @ cw2[128x64]
    f32x16 c0, c1;
    #pragma unroll
    for (int i = 0; i < 16; i++) { c0[i] = 0.0f; c1[i] = 0.0f; }
    #pragma unroll
    for (int s = 0; s < 8; s++) {
        const short8 a = *(const short8*)&Hs[r * HLD2 + 16 * s + 8 * hi];
        const short8 b0 = *(const short8*)&cw2f[(s * 2 + 0) * 512 + lane * 8];
        const short8 b1v = *(const short8*)&cw2f[(s * 2 + 1) * 512 + lane * 8];
        c0 = __builtin_amdgcn_mfma_f32_32x32x16_bf16(a, b0, c0, 0, 0, 0);
        c1 = __builtin_amdgcn_mfma_f32_32x32x16_bf16(a, b1v, c1, 0, 0, 0);
    }
    const float bb0 = cb2[r], bb1 = cb2[32 + r];
    #pragma unroll
    for (int g = 0; g < 16; g++) {
        const int rr = (g & 3) + 8 * (g >> 2) + 4 * hi;
        h_bf[(size_t)(qb + rr) * HHDIM + r]      = f2bf(fmaxf(c0[g] + bb0, 0.0f));
        h_bf[(size_t)(qb + rr) * HHDIM + 32 + r] = f2bf(fmaxf(c1[g] + bb1, 0.0f));
    }
}

// ---------------------------------------------------------------------------
// MFMA scorer: [B,192] @ sw1[0:192] (bf16 MFMA) + fp32 rank-1 (d_norm col),
// relu, fp32 dot with sw2, shfl-reduce. One 32-b tile per 64-thread block.
// ---------------------------------------------------------------------------
__global__ __launch_bounds__(64, 2)
void score_mfma(const short* __restrict__ h_bf, const float* __restrict__ dnorm,
                const short* __restrict__ sw1f, const float* __restrict__ sw1,
                const float* __restrict__ sb1, const float* __restrict__ sw2,
                const float* __restrict__ sb2, float* __restrict__ out)
{
    const int lane = threadIdx.x & 63;
    const int r = lane & 31, hi = lane >> 5;
    const int bb = blockIdx.x * 32;

    f32x16 acc[4];
    #pragma unroll
    for (int n = 0; n < 4; n++)
        #pragma unroll
        for (int i = 0; i < 16; i++) acc[n][i] = 0.0f;

    const short* arow = h_bf + (size_t)(bb + r) * 192 + 8 * hi;
    #pragma unroll
    for (int s = 0; s < 12; s++) {
        const short8 a = *(const short8*)(arow + 16 * s);
        #pragma unroll
        for (int n = 0; n < 4; n++) {
            const short8 bf = *(const short8*)&sw1f[(s * 4 + n) * 512 + lane * 8];
            acc[n] = __builtin_amdgcn_mfma_f32_32x32x16_bf16(a, bf, acc[n], 0, 0, 0);
        }
    }

    float sb1c[4], swr[4], sw2c[4];
    #pragma unroll
    for (int n = 0; n < 4; n++) {
        sb1c[n] = sb1[32 * n + r];
        swr[n]  = sw1[192 * HDIM + 32 * n + r];   // d_norm row of sw1
        sw2c[n] = sw2[32 * n + r];
    }
    const float sb2v = sb2[0];

    #pragma unroll
    for (int g = 0; g < 16; g++) {
        const int rr = (g & 3) + 8 * (g >> 2) + 4 * hi;   // b-row (uniform per half)
        const float dn = dnorm[bb + rr];
        float p = 0.0f;
        #pragma unroll
        for (int n = 0; n < 4; n++)
            p += fmaxf(acc[n][g] + sb1c[n] + dn * swr[n], 0.0f) * sw2c[n];
        p += __shfl_xor(p, 1);  p += __shfl_xor(p, 2);  p += __shfl_xor(p, 4);
        p += __shfl_xor(p, 8);  p += __shfl_xor(p, 16);
        if (r == 0) out[bb + rr] = p + sb2v;
    }
}

// ---------------------------------------------------------------------------
extern "C" void kernel_launch(void* const* d_in, const int* in_sizes, int n_in,
                              void* d_out, int out_size, void* d_ws, size_t ws_size,
                              hipStream_t stream)
{
    const float* x     = (const float*)d_in[0];
    const float* dnorm = (const float*)d_in[1];
    const float* demb  = (const float*)d_in[2];
    const float* piw1  = (const float*)d_in[3];
    const float* pib1  = (const float*)d_in[4];
    const float* piw2  = (const float*)d_in[5];
    const float* pib2  = (const float*)d_in[6];
    const float* pow1  = (const float*)d_in[7];
    const float* pob1  = (const float*)d_in[8];
    const float* pow2  = (const float*)d_in[9];
    const float* pob2  = (const float*)d_in[10];
    const float* cw1   = (const float*)d_in[11];
    const float* cb1   = (const float*)d_in[12];
    const float* cw2   = (const float*)d_in[13];
    const float* cb2   = (const float*)d_in[14];
    const float* sw1   = (const float*)d_in[15];
    const float* sb1   = (const float*)d_in[16];
    const float* sw2   = (const float*)d_in[17];
    const float* sb2   = (const float*)d_in[18];
    const int* node_ids = (const int*)d_in[19];
    const int* times    = (const int*)d_in[20];
    const int* in_u     = (const int*)d_in[21];
    const int* in_tau   = (const int*)d_in[22];
    const int* in_mask  = (const int*)d_in[23];
    const int* out_u    = (const int*)d_in[24];
    const int* out_tau  = (const int*)d_in[25];
    const int* out_mask = (const int*)d_in[26];

    float* ws      = (float*)d_ws;
    float* min_ws  = ws;                          // QQ*64 floats
    float* mout_ws = ws + (size_t)QQ * MDIM;      // QQ*64 floats
    short* h_bf    = (short*)(ws + (size_t)2 * QQ * MDIM);   // BB*192 bf16
    short* wpack   = (short*)(ws + (size_t)2 * QQ * MDIM + (size_t)BB * 192 / 2);
    short* cw1f    = wpack;            // 64 frags * 512 = 32768 shorts
    short* cw2f    = wpack + 32768;    // 16 frags -> 8192
    short* sw1f    = wpack + 40960;    // 48 frags -> 24576
    float* out     = (float*)d_out;

    pack_kernel<<<32, 256, 0, stream>>>(cw1, cw2, sw1, cw1f, cw2f, sw1f);
    agg_fused_kernel<<<2 * AGRID, 256, 0, stream>>>(x, demb,
                                                    piw1, pib1, piw2, pib2,
                                                    pow1, pob1, pow2, pob2,
                                                    times,
                                                    in_u, in_tau, in_mask,
                                                    out_u, out_tau, out_mask,
                                                    min_ws, mout_ws);
    combine_mfma<<<QQ / 32, 64, 0, stream>>>(x, node_ids, times, min_ws, mout_ws,
                                             cw1f, cb1, cw2f, cb2, h_bf);
    score_mfma<<<BB / 32, 64, 0, stream>>>(h_bf, dnorm, sw1f, sw1, sb1, sw2, sb2, out);
}